// Round 7
// baseline (579.333 us; speedup 1.0000x reference)
//
#include <hip/hip_runtime.h>

#define N_V  20000
#define B_   8
#define F_   64
#define K_   6
#define OUT_ 64
#define NNZ_ 320000
#define BF   512    // B_*F_
#define NSLICE 8
#define SLICE_W 2500
#define NPAIR (N_V / 2)            // 10000 row pairs
#define NBUK (NPAIR * NSLICE)      // 80000 buckets
#define CHEB_WAVES 8192            // 2048 blocks x 4 waves = exactly full residency

typedef unsigned short ushort_t;
typedef unsigned int   uint_t;

using frag_ab = __attribute__((ext_vector_type(8))) short;  // 8 bf16 (4 VGPRs)
using frag_cd = __attribute__((ext_vector_type(4))) float;  // 4 f32 acc

// ---- bf16 helpers ----
__device__ __forceinline__ ushort_t f2bf(float f) {          // round-to-nearest-even
    uint_t u = __float_as_uint(f);
    u += 0x7FFFu + ((u >> 16) & 1u);
    return (ushort_t)(u >> 16);
}
__device__ __forceinline__ uint_t pack2(float lo, float hi) {
    return (uint_t)f2bf(lo) | ((uint_t)f2bf(hi) << 16);
}
__device__ __forceinline__ void unpack2(uint_t u, float& lo, float& hi) {
    lo = __uint_as_float(u << 16);
    hi = __uint_as_float(u & 0xFFFF0000u);
}

// ---------------- fused prep + hist ----------------
// blocks [0,20000):   x -> X0 bf16 (T layout [n][b][f])
// blocks [20000,20096): W -> Wfrag MFMA B-fragments
// blocks [20096,21346): histogram of edge keys (pair-major, slice-ordered)
__global__ void prep_hist(const float* __restrict__ x, uint_t* __restrict__ X0,
                          const float* __restrict__ W, ushort_t* __restrict__ Wfrag,
                          const int* __restrict__ rows, const int* __restrict__ cols,
                          int* __restrict__ counts) {
    int blk = blockIdx.x;
    if (blk < 20000) {
        int idx = blk * 256 + threadIdx.x;      // over N_V*B_*32
        int f2 = idx & 31;
        int b  = (idx >> 5) & 7;
        int n  = idx >> 8;
        float2 v = *(const float2*)&x[((size_t)b * N_V + n) * F_ + f2 * 2];
        X0[n * 256 + b * 32 + f2] = pack2(v.x, v.y);
    } else if (blk < 20096) {
        int idx = (blk - 20000) * 256 + threadIdx.x;
        if (idx < 12 * 4 * 64 * 8) {
            int j    = idx & 7;
            int lane = (idx >> 3) & 63;
            int ct   = (idx >> 9) & 3;
            int s    = idx >> 11;
            int o     = ct * 16 + (lane & 15);
            int kglob = s * 32 + ((lane >> 4) & 3) * 8 + j;
            Wfrag[idx] = f2bf(W[o * (K_ * F_) + kglob]);
        }
    } else {
        int e = (blk - 20096) * 256 + threadIdx.x;
        if (e < NNZ_) {
            int key = (rows[e] >> 1) * NSLICE + cols[e] / SLICE_W;
            atomicAdd(&counts[key], 1);
        }
    }
}

// ---------------- single-block scan over 80000 buckets (two-pass) ----------------
// bp[i] = exclusive prefix, bp[NBUK] = total, cursor[i] = bucket start for scatter.
__global__ __launch_bounds__(1024) void scan80k(const int* __restrict__ counts,
                                                int* __restrict__ bp,
                                                int* __restrict__ cursor) {
    __shared__ int buf[1024];
    const int tid = threadIdx.x;
    const int base = tid * 79;                  // 1024*79 = 80896 >= NBUK
    int s = 0;
    for (int k = 0; k < 79; ++k) {
        int i = base + k;
        if (i < NBUK) s += counts[i];
    }
    buf[tid] = s;
    __syncthreads();
    for (int off = 1; off < 1024; off <<= 1) {
        int t = buf[tid];
        int add = (tid >= off) ? buf[tid - off] : 0;
        __syncthreads();
        buf[tid] = t + add;
        __syncthreads();
    }
    int run = buf[tid] - s;                     // exclusive block offset
    for (int k = 0; k < 79; ++k) {
        int i = base + k;
        if (i < NBUK) {
            bp[i] = run;
            cursor[i] = run;
            run += counts[i];
        }
    }
    if (tid == 1023) bp[NBUK] = buf[1023];
}

// edges packed: {col | (row&1)<<15, val_bits}   (col < 20000 < 2^15)
__global__ void scatter_kernel(const int* __restrict__ rows, const int* __restrict__ cols,
                               const float* __restrict__ vals, int* __restrict__ cursor,
                               int2* __restrict__ edges) {
    int e = blockIdx.x * 256 + threadIdx.x;
    if (e < NNZ_) {
        int c = cols[e];
        int r = rows[e];
        int key = (r >> 1) * NSLICE + c / SLICE_W;
        int pos = atomicAdd(&cursor[key], 1);
        int2 pe;
        pe.x = c | ((r & 1) << 15);
        pe.y = __float_as_int(vals[e]);
        edges[pos] = pe;
    }
}

// -------- SpMM: 1 row-pair per wave, batch-8 gathers in flight, grid-stride pairs --------
// Exactly 8192 waves (full residency, no tail rounds); waves with pair+8192 < 10000 do 2.
template <bool RECUR>
__global__ __launch_bounds__(256) void cheb_pair(const int* __restrict__ bp,
                                                 const int2* __restrict__ edges,
                                                 const ushort_t* __restrict__ Tprev,
                                                 const ushort_t* __restrict__ Tpp,
                                                 ushort_t* __restrict__ Tout) {
    const int wave = threadIdx.x >> 6, lane = threadIdx.x & 63;
    const int fo = lane * 8;                        // bf16 offset (16B per lane)

    for (int pair = blockIdx.x * 4 + wave; pair < NPAIR; pair += CHEB_WAVES) {
        const int n0 = pair * 2;
        const int st = bp[pair * NSLICE];
        const int en = bp[pair * NSLICE + NSLICE];  // whole pair stream, slice-ordered

        float a0[8], a1[8];
#pragma unroll
        for (int i = 0; i < 8; ++i) { a0[i] = 0.f; a1[i] = 0.f; }

        for (int j = st; j < en; j += 8) {
            int2 E[8];
#pragma unroll
            for (int q = 0; q < 8; ++q) {
                E[q] = edges[min(j + q, en - 1)];
            }
            uint4 u[8];
#pragma unroll
            for (int q = 0; q < 8; ++q) {
                u[q] = *(const uint4*)(Tprev + (size_t)(E[q].x & 0x7FFF) * BF + fo);
            }
#pragma unroll
            for (int q = 0; q < 8; ++q) {
                const float v  = (j + q < en) ? __int_as_float(E[q].y) : 0.f;
                const float p0 = (E[q].x & 0x8000) ? 0.f : v;
                const float p1 = (E[q].x & 0x8000) ? v : 0.f;
                float e[8];
                unpack2(u[q].x, e[0], e[1]); unpack2(u[q].y, e[2], e[3]);
                unpack2(u[q].z, e[4], e[5]); unpack2(u[q].w, e[6], e[7]);
#pragma unroll
                for (int i = 0; i < 8; ++i) {
                    a0[i] = fmaf(p0, e[i], a0[i]);
                    a1[i] = fmaf(p1, e[i], a1[i]);
                }
            }
        }

        // epilogue: row n0 from a0, row n0+1 from a1
        {
            float res[8];
#pragma unroll
            for (int i = 0; i < 8; ++i) res[i] = a0[i];
            if (RECUR) {
                uint4 up = *(const uint4*)(Tpp + (size_t)n0 * BF + fo);
                float ep[8];
                unpack2(up.x, ep[0], ep[1]); unpack2(up.y, ep[2], ep[3]);
                unpack2(up.z, ep[4], ep[5]); unpack2(up.w, ep[6], ep[7]);
#pragma unroll
                for (int i = 0; i < 8; ++i) res[i] = 2.f * res[i] - ep[i];
            }
            uint4 st4;
            st4.x = pack2(res[0], res[1]);
            st4.y = pack2(res[2], res[3]);
            st4.z = pack2(res[4], res[5]);
            st4.w = pack2(res[6], res[7]);
            *(uint4*)(Tout + (size_t)n0 * BF + fo) = st4;
        }
        {
            float res[8];
#pragma unroll
            for (int i = 0; i < 8; ++i) res[i] = a1[i];
            if (RECUR) {
                uint4 up = *(const uint4*)(Tpp + (size_t)(n0 + 1) * BF + fo);
                float ep[8];
                unpack2(up.x, ep[0], ep[1]); unpack2(up.y, ep[2], ep[3]);
                unpack2(up.z, ep[4], ep[5]); unpack2(up.w, ep[6], ep[7]);
#pragma unroll
                for (int i = 0; i < 8; ++i) res[i] = 2.f * res[i] - ep[i];
            }
            uint4 st4;
            st4.x = pack2(res[0], res[1]);
            st4.y = pack2(res[2], res[3]);
            st4.z = pack2(res[4], res[5]);
            st4.w = pack2(res[6], res[7]);
            *(uint4*)(Tout + (size_t)(n0 + 1) * BF + fo) = st4;
        }
    }
}

// ---------------- FC via MFMA 16x16x32 bf16, 2 tiles/wave ----------------
__global__ __launch_bounds__(256) void fc_mfma(const ushort_t* __restrict__ X0,
                                               const ushort_t* __restrict__ T1,
                                               const ushort_t* __restrict__ T2,
                                               const ushort_t* __restrict__ T3,
                                               const ushort_t* __restrict__ T4,
                                               const ushort_t* __restrict__ T5,
                                               const ushort_t* __restrict__ Wfrag,
                                               const float* __restrict__ bias,
                                               float* __restrict__ out) {
    const int wave = threadIdx.x >> 6, lane = threadIdx.x & 63;
    const int quad = lane >> 4, col = lane & 15;
    const int tb = blockIdx.x * 128 + wave * 32;      // 2 tiles: tb, tb+16
    const int r0 = tb + col, r1 = tb + 16 + col;
    const ushort_t* Tbuf[6] = {X0, T1, T2, T3, T4, T5};

    frag_cd acc0[4], acc1[4];
#pragma unroll
    for (int ct = 0; ct < 4; ++ct) {
        acc0[ct] = (frag_cd){0.f, 0.f, 0.f, 0.f};
        acc1[ct] = (frag_cd){0.f, 0.f, 0.f, 0.f};
    }

#pragma unroll
    for (int s = 0; s < 12; ++s) {
        const int f0 = (s & 1) * 32 + quad * 8;
        frag_ab fa0 = *(const frag_ab*)(Tbuf[s >> 1] + (size_t)r0 * F_ + f0);
        frag_ab fa1 = *(const frag_ab*)(Tbuf[s >> 1] + (size_t)r1 * F_ + f0);
#pragma unroll
        for (int ct = 0; ct < 4; ++ct) {
            frag_ab bfr = *(const frag_ab*)(Wfrag + (((s * 4 + ct) * 64 + lane) << 3));
            acc0[ct] = __builtin_amdgcn_mfma_f32_16x16x32_bf16(fa0, bfr, acc0[ct], 0, 0, 0);
            acc1[ct] = __builtin_amdgcn_mfma_f32_16x16x32_bf16(fa1, bfr, acc1[ct], 0, 0, 0);
        }
    }

    // C/D: col = lane&15, row = quad*4 + reg
#pragma unroll
    for (int ct = 0; ct < 4; ++ct) {
        const int o = ct * 16 + col;
        const float bv = bias[o];
#pragma unroll
        for (int reg = 0; reg < 4; ++reg) {
            int ra = tb + quad * 4 + reg;
            int rb = ra + 16;
            out[(size_t)(ra & 7) * N_V * OUT_ + (size_t)(ra >> 3) * OUT_ + o] = acc0[ct][reg] + bv;
            out[(size_t)(rb & 7) * N_V * OUT_ + (size_t)(rb >> 3) * OUT_ + o] = acc1[ct][reg] + bv;
        }
    }
}

// ---------------- launcher ----------------

extern "C" void kernel_launch(void* const* d_in, const int* in_sizes, int n_in,
                              void* d_out, int out_size, void* d_ws, size_t ws_size,
                              hipStream_t stream) {
    const float* x    = (const float*)d_in[0];
    const int*   rows = (const int*)  d_in[1];
    const int*   cols = (const int*)  d_in[2];
    const float* vals = (const float*)d_in[3];
    const float* W    = (const float*)d_in[4];
    const float* bias = (const float*)d_in[5];
    float* out = (float*)d_out;

    const size_t TSZ = (size_t)N_V * BF;           // bf16 elements per T buffer
    ushort_t* T1 = (ushort_t*)d_ws;
    ushort_t* T2 = T1 + TSZ;
    ushort_t* T3 = T2 + TSZ;
    ushort_t* T4 = T3 + TSZ;
    ushort_t* T5 = T4 + TSZ;
    ushort_t* X0 = T5 + TSZ;
    ushort_t* Wfrag = X0 + TSZ;                    // 24576 ushorts
    int* counts    = (int*)(Wfrag + 24576);        // NBUK
    int* bp        = counts + NBUK;                // NBUK+1 (+pad)
    int* cursor    = bp + NBUK + 64;               // NBUK
    int2* edges    = (int2*)(cursor + NBUK);       // NNZ int2 (no padding needed)

    hipMemsetAsync(counts, 0, NBUK * sizeof(int), stream);
    prep_hist<<<20096 + 1250, 256, 0, stream>>>(x, (uint_t*)X0, W, Wfrag, rows, cols, counts);
    scan80k<<<1, 1024, 0, stream>>>(counts, bp, cursor);
    scatter_kernel<<<(NNZ_ + 255) / 256, 256, 0, stream>>>(rows, cols, vals, cursor, edges);

    cheb_pair<false><<<CHEB_WAVES / 4, 256, 0, stream>>>(bp, edges, X0, nullptr, T1);
    cheb_pair<true ><<<CHEB_WAVES / 4, 256, 0, stream>>>(bp, edges, T1, X0, T2);
    cheb_pair<true ><<<CHEB_WAVES / 4, 256, 0, stream>>>(bp, edges, T2, T1, T3);
    cheb_pair<true ><<<CHEB_WAVES / 4, 256, 0, stream>>>(bp, edges, T3, T2, T4);
    cheb_pair<true ><<<CHEB_WAVES / 4, 256, 0, stream>>>(bp, edges, T4, T3, T5);

    fc_mfma<<<(N_V * B_) / 128, 256, 0, stream>>>(X0, T1, T2, T3, T4, T5, Wfrag, bias, out);
}

// Round 8
// 387.397 us; speedup vs baseline: 1.4955x; 1.4955x over previous
//
#include <hip/hip_runtime.h>

#define N_V  20000
#define B_   8
#define F_   64
#define K_   6
#define OUT_ 64
#define NNZ_ 320000
#define BF   512    // B_*F_
#define NSLICE 8
#define SLICE_W 2500
#define NPAIR (N_V / 2)            // 10000 row pairs
#define NBUK (NPAIR * NSLICE)      // 80000 buckets
#define SCANB 79                   // ceil(NBUK/1024)
#define CHEB_WAVES 8192            // 2048 blocks x 4 waves = exactly full residency

typedef unsigned short ushort_t;
typedef unsigned int   uint_t;

using frag_ab = __attribute__((ext_vector_type(8))) short;  // 8 bf16 (4 VGPRs)
using frag_cd = __attribute__((ext_vector_type(4))) float;  // 4 f32 acc

// ---- bf16 helpers ----
__device__ __forceinline__ ushort_t f2bf(float f) {          // round-to-nearest-even
    uint_t u = __float_as_uint(f);
    u += 0x7FFFu + ((u >> 16) & 1u);
    return (ushort_t)(u >> 16);
}
__device__ __forceinline__ uint_t pack2(float lo, float hi) {
    return (uint_t)f2bf(lo) | ((uint_t)f2bf(hi) << 16);
}
__device__ __forceinline__ void unpack2(uint_t u, float& lo, float& hi) {
    lo = __uint_as_float(u << 16);
    hi = __uint_as_float(u & 0xFFFF0000u);
}

// ---------------- fused prep + hist ----------------
// blocks [0,20000):   x -> X0 bf16 (T layout [n][b][f])
// blocks [20000,20096): W -> Wfrag MFMA B-fragments
// blocks [20096,21346): histogram of edge keys (pair-major, slice-ordered)
__global__ void prep_hist(const float* __restrict__ x, uint_t* __restrict__ X0,
                          const float* __restrict__ W, ushort_t* __restrict__ Wfrag,
                          const int* __restrict__ rows, const int* __restrict__ cols,
                          int* __restrict__ counts) {
    int blk = blockIdx.x;
    if (blk < 20000) {
        int idx = blk * 256 + threadIdx.x;      // over N_V*B_*32
        int f2 = idx & 31;
        int b  = (idx >> 5) & 7;
        int n  = idx >> 8;
        float2 v = *(const float2*)&x[((size_t)b * N_V + n) * F_ + f2 * 2];
        X0[n * 256 + b * 32 + f2] = pack2(v.x, v.y);
    } else if (blk < 20096) {
        int idx = (blk - 20000) * 256 + threadIdx.x;
        if (idx < 12 * 4 * 64 * 8) {
            int j    = idx & 7;
            int lane = (idx >> 3) & 63;
            int ct   = (idx >> 9) & 3;
            int s    = idx >> 11;
            int o     = ct * 16 + (lane & 15);
            int kglob = s * 32 + ((lane >> 4) & 3) * 8 + j;
            Wfrag[idx] = f2bf(W[o * (K_ * F_) + kglob]);
        }
    } else {
        int e = (blk - 20096) * 256 + threadIdx.x;
        if (e < NNZ_) {
            int key = (rows[e] >> 1) * NSLICE + cols[e] / SLICE_W;
            atomicAdd(&counts[key], 1);
        }
    }
}

// ---------------- 3-dispatch parallel scan over NBUK buckets (proven fast) ----------------
__global__ __launch_bounds__(1024) void scan1(const int* __restrict__ counts,
                                              int* __restrict__ incl, int* __restrict__ bsum) {
    __shared__ int buf[1024];
    int tid = threadIdx.x;
    int i = blockIdx.x * 1024 + tid;
    int c = (i < NBUK) ? counts[i] : 0;
    buf[tid] = c;
    __syncthreads();
    for (int off = 1; off < 1024; off <<= 1) {
        int t = buf[tid];
        int add = (tid >= off) ? buf[tid - off] : 0;
        __syncthreads();
        buf[tid] = t + add;
        __syncthreads();
    }
    if (i < NBUK) incl[i] = buf[tid];
    if (tid == 1023) bsum[blockIdx.x] = buf[1023];
}

__global__ __launch_bounds__(256) void scan2(int* __restrict__ bsum) {
    __shared__ int buf[256];
    int tid = threadIdx.x;
    int c = (tid < SCANB) ? bsum[tid] : 0;
    buf[tid] = c;
    __syncthreads();
    for (int off = 1; off < 256; off <<= 1) {
        int t = buf[tid];
        int add = (tid >= off) ? buf[tid - off] : 0;
        __syncthreads();
        buf[tid] = t + add;
        __syncthreads();
    }
    if (tid < SCANB) bsum[tid] = buf[tid] - c;   // exclusive block offsets
}

__global__ __launch_bounds__(1024) void scan3(const int* __restrict__ counts,
                                              const int* __restrict__ bsum,
                                              int* __restrict__ bp, int* __restrict__ cursor) {
    int tid = threadIdx.x;
    int i = blockIdx.x * 1024 + tid;
    if (i < NBUK) {
        int p = bsum[blockIdx.x] + cursor[i];   // global inclusive prefix
        bp[i + 1] = p;
        cursor[i] = p - counts[i];              // bucket start for scatter
    }
    if (i == 0) bp[0] = 0;
}

// edges packed: {col | (row&1)<<15, val_bits}   (col < 20000 < 2^15)
__global__ void scatter_kernel(const int* __restrict__ rows, const int* __restrict__ cols,
                               const float* __restrict__ vals, int* __restrict__ cursor,
                               int2* __restrict__ edges) {
    int e = blockIdx.x * 256 + threadIdx.x;
    if (e < NNZ_) {
        int c = cols[e];
        int r = rows[e];
        int key = (r >> 1) * NSLICE + c / SLICE_W;
        int pos = atomicAdd(&cursor[key], 1);
        int2 pe;
        pe.x = c | ((r & 1) << 15);
        pe.y = __float_as_int(vals[e]);
        edges[pos] = pe;
    }
}

// -------- SpMM: 1 row-pair per wave, batch-8 gathers in flight, grid-stride pairs --------
// Exactly 8192 waves (full residency, no tail rounds); 1808 waves do a second pair.
template <bool RECUR>
__global__ __launch_bounds__(256) void cheb_pair(const int* __restrict__ bp,
                                                 const int2* __restrict__ edges,
                                                 const ushort_t* __restrict__ Tprev,
                                                 const ushort_t* __restrict__ Tpp,
                                                 ushort_t* __restrict__ Tout) {
    const int wave = threadIdx.x >> 6, lane = threadIdx.x & 63;
    const int fo = lane * 8;                        // bf16 offset (16B per lane)

    for (int pair = blockIdx.x * 4 + wave; pair < NPAIR; pair += CHEB_WAVES) {
        const int n0 = pair * 2;
        const int st = bp[pair * NSLICE];
        const int en = bp[pair * NSLICE + NSLICE];  // whole pair stream, slice-ordered

        float a0[8], a1[8];
#pragma unroll
        for (int i = 0; i < 8; ++i) { a0[i] = 0.f; a1[i] = 0.f; }

        for (int j = st; j < en; j += 8) {
            int2 E[8];
#pragma unroll
            for (int q = 0; q < 8; ++q) {
                E[q] = edges[min(j + q, en - 1)];
            }
            uint4 u[8];
#pragma unroll
            for (int q = 0; q < 8; ++q) {
                u[q] = *(const uint4*)(Tprev + (size_t)(E[q].x & 0x7FFF) * BF + fo);
            }
#pragma unroll
            for (int q = 0; q < 8; ++q) {
                const float v  = (j + q < en) ? __int_as_float(E[q].y) : 0.f;
                const float p0 = (E[q].x & 0x8000) ? 0.f : v;
                const float p1 = (E[q].x & 0x8000) ? v : 0.f;
                float e[8];
                unpack2(u[q].x, e[0], e[1]); unpack2(u[q].y, e[2], e[3]);
                unpack2(u[q].z, e[4], e[5]); unpack2(u[q].w, e[6], e[7]);
#pragma unroll
                for (int i = 0; i < 8; ++i) {
                    a0[i] = fmaf(p0, e[i], a0[i]);
                    a1[i] = fmaf(p1, e[i], a1[i]);
                }
            }
        }

        // epilogue: row n0 from a0, row n0+1 from a1
        {
            float res[8];
#pragma unroll
            for (int i = 0; i < 8; ++i) res[i] = a0[i];
            if (RECUR) {
                uint4 up = *(const uint4*)(Tpp + (size_t)n0 * BF + fo);
                float ep[8];
                unpack2(up.x, ep[0], ep[1]); unpack2(up.y, ep[2], ep[3]);
                unpack2(up.z, ep[4], ep[5]); unpack2(up.w, ep[6], ep[7]);
#pragma unroll
                for (int i = 0; i < 8; ++i) res[i] = 2.f * res[i] - ep[i];
            }
            uint4 st4;
            st4.x = pack2(res[0], res[1]);
            st4.y = pack2(res[2], res[3]);
            st4.z = pack2(res[4], res[5]);
            st4.w = pack2(res[6], res[7]);
            *(uint4*)(Tout + (size_t)n0 * BF + fo) = st4;
        }
        {
            float res[8];
#pragma unroll
            for (int i = 0; i < 8; ++i) res[i] = a1[i];
            if (RECUR) {
                uint4 up = *(const uint4*)(Tpp + (size_t)(n0 + 1) * BF + fo);
                float ep[8];
                unpack2(up.x, ep[0], ep[1]); unpack2(up.y, ep[2], ep[3]);
                unpack2(up.z, ep[4], ep[5]); unpack2(up.w, ep[6], ep[7]);
#pragma unroll
                for (int i = 0; i < 8; ++i) res[i] = 2.f * res[i] - ep[i];
            }
            uint4 st4;
            st4.x = pack2(res[0], res[1]);
            st4.y = pack2(res[2], res[3]);
            st4.z = pack2(res[4], res[5]);
            st4.w = pack2(res[6], res[7]);
            *(uint4*)(Tout + (size_t)(n0 + 1) * BF + fo) = st4;
        }
    }
}

// ---------------- FC via MFMA 16x16x32 bf16, 2 tiles/wave ----------------
__global__ __launch_bounds__(256) void fc_mfma(const ushort_t* __restrict__ X0,
                                               const ushort_t* __restrict__ T1,
                                               const ushort_t* __restrict__ T2,
                                               const ushort_t* __restrict__ T3,
                                               const ushort_t* __restrict__ T4,
                                               const ushort_t* __restrict__ T5,
                                               const ushort_t* __restrict__ Wfrag,
                                               const float* __restrict__ bias,
                                               float* __restrict__ out) {
    const int wave = threadIdx.x >> 6, lane = threadIdx.x & 63;
    const int quad = lane >> 4, col = lane & 15;
    const int tb = blockIdx.x * 128 + wave * 32;      // 2 tiles: tb, tb+16
    const int r0 = tb + col, r1 = tb + 16 + col;
    const ushort_t* Tbuf[6] = {X0, T1, T2, T3, T4, T5};

    frag_cd acc0[4], acc1[4];
#pragma unroll
    for (int ct = 0; ct < 4; ++ct) {
        acc0[ct] = (frag_cd){0.f, 0.f, 0.f, 0.f};
        acc1[ct] = (frag_cd){0.f, 0.f, 0.f, 0.f};
    }

#pragma unroll
    for (int s = 0; s < 12; ++s) {
        const int f0 = (s & 1) * 32 + quad * 8;
        frag_ab fa0 = *(const frag_ab*)(Tbuf[s >> 1] + (size_t)r0 * F_ + f0);
        frag_ab fa1 = *(const frag_ab*)(Tbuf[s >> 1] + (size_t)r1 * F_ + f0);
#pragma unroll
        for (int ct = 0; ct < 4; ++ct) {
            frag_ab bfr = *(const frag_ab*)(Wfrag + (((s * 4 + ct) * 64 + lane) << 3));
            acc0[ct] = __builtin_amdgcn_mfma_f32_16x16x32_bf16(fa0, bfr, acc0[ct], 0, 0, 0);
            acc1[ct] = __builtin_amdgcn_mfma_f32_16x16x32_bf16(fa1, bfr, acc1[ct], 0, 0, 0);
        }
    }

    // C/D: col = lane&15, row = quad*4 + reg
#pragma unroll
    for (int ct = 0; ct < 4; ++ct) {
        const int o = ct * 16 + col;
        const float bv = bias[o];
#pragma unroll
        for (int reg = 0; reg < 4; ++reg) {
            int ra = tb + quad * 4 + reg;
            int rb = ra + 16;
            out[(size_t)(ra & 7) * N_V * OUT_ + (size_t)(ra >> 3) * OUT_ + o] = acc0[ct][reg] + bv;
            out[(size_t)(rb & 7) * N_V * OUT_ + (size_t)(rb >> 3) * OUT_ + o] = acc1[ct][reg] + bv;
        }
    }
}

// ---------------- launcher ----------------

extern "C" void kernel_launch(void* const* d_in, const int* in_sizes, int n_in,
                              void* d_out, int out_size, void* d_ws, size_t ws_size,
                              hipStream_t stream) {
    const float* x    = (const float*)d_in[0];
    const int*   rows = (const int*)  d_in[1];
    const int*   cols = (const int*)  d_in[2];
    const float* vals = (const float*)d_in[3];
    const float* W    = (const float*)d_in[4];
    const float* bias = (const float*)d_in[5];
    float* out = (float*)d_out;

    const size_t TSZ = (size_t)N_V * BF;           // bf16 elements per T buffer
    ushort_t* T1 = (ushort_t*)d_ws;
    ushort_t* T2 = T1 + TSZ;
    ushort_t* T3 = T2 + TSZ;
    ushort_t* T4 = T3 + TSZ;
    ushort_t* T5 = T4 + TSZ;
    ushort_t* X0 = T5 + TSZ;
    ushort_t* Wfrag = X0 + TSZ;                    // 24576 ushorts
    int* counts    = (int*)(Wfrag + 24576);        // NBUK
    int* bp        = counts + NBUK;                // NBUK+1 (+pad)
    int* cursor    = bp + NBUK + 64;               // NBUK
    int* bsum      = cursor + NBUK;                // 256
    int2* edges    = (int2*)(bsum + 256);          // NNZ int2

    hipMemsetAsync(counts, 0, NBUK * sizeof(int), stream);
    prep_hist<<<20096 + 1250, 256, 0, stream>>>(x, (uint_t*)X0, W, Wfrag, rows, cols, counts);
    scan1<<<SCANB, 1024, 0, stream>>>(counts, cursor, bsum);
    scan2<<<1, 256, 0, stream>>>(bsum);
    scan3<<<SCANB, 1024, 0, stream>>>(counts, bsum, bp, cursor);
    scatter_kernel<<<(NNZ_ + 255) / 256, 256, 0, stream>>>(rows, cols, vals, cursor, edges);

    cheb_pair<false><<<CHEB_WAVES / 4, 256, 0, stream>>>(bp, edges, X0, nullptr, T1);
    cheb_pair<true ><<<CHEB_WAVES / 4, 256, 0, stream>>>(bp, edges, T1, X0, T2);
    cheb_pair<true ><<<CHEB_WAVES / 4, 256, 0, stream>>>(bp, edges, T2, T1, T3);
    cheb_pair<true ><<<CHEB_WAVES / 4, 256, 0, stream>>>(bp, edges, T3, T2, T4);
    cheb_pair<true ><<<CHEB_WAVES / 4, 256, 0, stream>>>(bp, edges, T4, T3, T5);

    fc_mfma<<<(N_V * B_) / 128, 256, 0, stream>>>(X0, T1, T2, T3, T4, T5, Wfrag, bias, out);
}

// Round 9
// 382.919 us; speedup vs baseline: 1.5129x; 1.0117x over previous
//
#include <hip/hip_runtime.h>

#define N_V  20000
#define B_   8
#define F_   64
#define K_   6
#define OUT_ 64
#define NNZ_ 320000
#define BF   512    // B_*F_
#define NPAIR (N_V / 2)            // 10000 row pairs
#define PCAP 128                   // edge capacity per pair (P(overflow) ~ 1e-40)
#define CHEB_WAVES 8192            // 2048 blocks x 4 waves

typedef unsigned short ushort_t;
typedef unsigned int   uint_t;

using frag_ab = __attribute__((ext_vector_type(8))) short;  // 8 bf16 (4 VGPRs)
using frag_cd = __attribute__((ext_vector_type(4))) float;  // 4 f32 acc

// ---- bf16 helpers ----
__device__ __forceinline__ ushort_t f2bf(float f) {          // round-to-nearest-even
    uint_t u = __float_as_uint(f);
    u += 0x7FFFu + ((u >> 16) & 1u);
    return (ushort_t)(u >> 16);
}
__device__ __forceinline__ uint_t pack2(float lo, float hi) {
    return (uint_t)f2bf(lo) | ((uint_t)f2bf(hi) << 16);
}
__device__ __forceinline__ void unpack2(uint_t u, float& lo, float& hi) {
    lo = __uint_as_float(u << 16);
    hi = __uint_as_float(u & 0xFFFF0000u);
}

// ---------------- fused prep: X0 convert + Wfrag pack + cnt zero ----------------
// blocks [0,20000):        x -> X0 bf16 (T layout [n][b][f])
// blocks [20000,20096):    W -> Wfrag MFMA B-fragments
// blocks [20096,20136):    zero the 10000 per-pair edge counters
__global__ void prep_kernel(const float* __restrict__ x, uint_t* __restrict__ X0,
                            const float* __restrict__ W, ushort_t* __restrict__ Wfrag,
                            int* __restrict__ cnt) {
    int blk = blockIdx.x;
    if (blk < 20000) {
        int idx = blk * 256 + threadIdx.x;      // over N_V*B_*32
        int f2 = idx & 31;
        int b  = (idx >> 5) & 7;
        int n  = idx >> 8;
        float2 v = *(const float2*)&x[((size_t)b * N_V + n) * F_ + f2 * 2];
        X0[n * 256 + b * 32 + f2] = pack2(v.x, v.y);
    } else if (blk < 20096) {
        int idx = (blk - 20000) * 256 + threadIdx.x;
        if (idx < 12 * 4 * 64 * 8) {
            int j    = idx & 7;
            int lane = (idx >> 3) & 63;
            int ct   = (idx >> 9) & 3;
            int s    = idx >> 11;
            int o     = ct * 16 + (lane & 15);
            int kglob = s * 32 + ((lane >> 4) & 3) * 8 + j;
            Wfrag[idx] = f2bf(W[o * (K_ * F_) + kglob]);
        }
    } else {
        int i = (blk - 20096) * 256 + threadIdx.x;
        if (i < NPAIR) cnt[i] = 0;
    }
}

// ---------------- scatter with fixed-capacity bump allocation (no hist/scan) ----------------
// edges packed: {col | (row&1)<<15, val_bits}   (col < 20000 < 2^15)
__global__ void scatter_kernel(const int* __restrict__ rows, const int* __restrict__ cols,
                               const float* __restrict__ vals, int* __restrict__ cnt,
                               int2* __restrict__ edges) {
    int e = blockIdx.x * 256 + threadIdx.x;
    if (e < NNZ_) {
        int c = cols[e];
        int r = rows[e];
        int pair = r >> 1;
        int pos = atomicAdd(&cnt[pair], 1);
        if (pos < PCAP) {                       // overflow guard (never fires statistically)
            int2 pe;
            pe.x = c | ((r & 1) << 15);
            pe.y = __float_as_int(vals[e]);
            edges[pair * PCAP + pos] = pe;
        }
    }
}

// -------- SpMM: 1 row-pair per wave, batch-8 gathers in flight, grid-stride pairs --------
template <bool RECUR>
__global__ __launch_bounds__(256) void cheb_pair(const int* __restrict__ cnt,
                                                 const int2* __restrict__ edges,
                                                 const ushort_t* __restrict__ Tprev,
                                                 const ushort_t* __restrict__ Tpp,
                                                 ushort_t* __restrict__ Tout) {
    const int wave = threadIdx.x >> 6, lane = threadIdx.x & 63;
    const int fo = lane * 8;                        // bf16 offset (16B per lane)

    for (int pair = blockIdx.x * 4 + wave; pair < NPAIR; pair += CHEB_WAVES) {
        const int n0 = pair * 2;
        const int st = pair * PCAP;
        const int en = st + min(cnt[pair], PCAP);

        float a0[8], a1[8];
#pragma unroll
        for (int i = 0; i < 8; ++i) { a0[i] = 0.f; a1[i] = 0.f; }

        for (int j = st; j < en; j += 8) {
            int2 E[8];
#pragma unroll
            for (int q = 0; q < 8; ++q) {
                E[q] = edges[min(j + q, en - 1)];
            }
            uint4 u[8];
#pragma unroll
            for (int q = 0; q < 8; ++q) {
                u[q] = *(const uint4*)(Tprev + (size_t)(E[q].x & 0x7FFF) * BF + fo);
            }
#pragma unroll
            for (int q = 0; q < 8; ++q) {
                const float v  = (j + q < en) ? __int_as_float(E[q].y) : 0.f;
                const float p0 = (E[q].x & 0x8000) ? 0.f : v;
                const float p1 = (E[q].x & 0x8000) ? v : 0.f;
                float e[8];
                unpack2(u[q].x, e[0], e[1]); unpack2(u[q].y, e[2], e[3]);
                unpack2(u[q].z, e[4], e[5]); unpack2(u[q].w, e[6], e[7]);
#pragma unroll
                for (int i = 0; i < 8; ++i) {
                    a0[i] = fmaf(p0, e[i], a0[i]);
                    a1[i] = fmaf(p1, e[i], a1[i]);
                }
            }
        }

        // epilogue: row n0 from a0, row n0+1 from a1
        {
            float res[8];
#pragma unroll
            for (int i = 0; i < 8; ++i) res[i] = a0[i];
            if (RECUR) {
                uint4 up = *(const uint4*)(Tpp + (size_t)n0 * BF + fo);
                float ep[8];
                unpack2(up.x, ep[0], ep[1]); unpack2(up.y, ep[2], ep[3]);
                unpack2(up.z, ep[4], ep[5]); unpack2(up.w, ep[6], ep[7]);
#pragma unroll
                for (int i = 0; i < 8; ++i) res[i] = 2.f * res[i] - ep[i];
            }
            uint4 st4;
            st4.x = pack2(res[0], res[1]);
            st4.y = pack2(res[2], res[3]);
            st4.z = pack2(res[4], res[5]);
            st4.w = pack2(res[6], res[7]);
            *(uint4*)(Tout + (size_t)n0 * BF + fo) = st4;
        }
        {
            float res[8];
#pragma unroll
            for (int i = 0; i < 8; ++i) res[i] = a1[i];
            if (RECUR) {
                uint4 up = *(const uint4*)(Tpp + (size_t)(n0 + 1) * BF + fo);
                float ep[8];
                unpack2(up.x, ep[0], ep[1]); unpack2(up.y, ep[2], ep[3]);
                unpack2(up.z, ep[4], ep[5]); unpack2(up.w, ep[6], ep[7]);
#pragma unroll
                for (int i = 0; i < 8; ++i) res[i] = 2.f * res[i] - ep[i];
            }
            uint4 st4;
            st4.x = pack2(res[0], res[1]);
            st4.y = pack2(res[2], res[3]);
            st4.z = pack2(res[4], res[5]);
            st4.w = pack2(res[6], res[7]);
            *(uint4*)(Tout + (size_t)(n0 + 1) * BF + fo) = st4;
        }
    }
}

// ---------------- FC via MFMA 16x16x32 bf16, 2 tiles/wave ----------------
__global__ __launch_bounds__(256) void fc_mfma(const ushort_t* __restrict__ X0,
                                               const ushort_t* __restrict__ T1,
                                               const ushort_t* __restrict__ T2,
                                               const ushort_t* __restrict__ T3,
                                               const ushort_t* __restrict__ T4,
                                               const ushort_t* __restrict__ T5,
                                               const ushort_t* __restrict__ Wfrag,
                                               const float* __restrict__ bias,
                                               float* __restrict__ out) {
    const int wave = threadIdx.x >> 6, lane = threadIdx.x & 63;
    const int quad = lane >> 4, col = lane & 15;
    const int tb = blockIdx.x * 128 + wave * 32;      // 2 tiles: tb, tb+16
    const int r0 = tb + col, r1 = tb + 16 + col;
    const ushort_t* Tbuf[6] = {X0, T1, T2, T3, T4, T5};

    frag_cd acc0[4], acc1[4];
#pragma unroll
    for (int ct = 0; ct < 4; ++ct) {
        acc0[ct] = (frag_cd){0.f, 0.f, 0.f, 0.f};
        acc1[ct] = (frag_cd){0.f, 0.f, 0.f, 0.f};
    }

#pragma unroll
    for (int s = 0; s < 12; ++s) {
        const int f0 = (s & 1) * 32 + quad * 8;
        frag_ab fa0 = *(const frag_ab*)(Tbuf[s >> 1] + (size_t)r0 * F_ + f0);
        frag_ab fa1 = *(const frag_ab*)(Tbuf[s >> 1] + (size_t)r1 * F_ + f0);
#pragma unroll
        for (int ct = 0; ct < 4; ++ct) {
            frag_ab bfr = *(const frag_ab*)(Wfrag + (((s * 4 + ct) * 64 + lane) << 3));
            acc0[ct] = __builtin_amdgcn_mfma_f32_16x16x32_bf16(fa0, bfr, acc0[ct], 0, 0, 0);
            acc1[ct] = __builtin_amdgcn_mfma_f32_16x16x32_bf16(fa1, bfr, acc1[ct], 0, 0, 0);
        }
    }

    // C/D: col = lane&15, row = quad*4 + reg
#pragma unroll
    for (int ct = 0; ct < 4; ++ct) {
        const int o = ct * 16 + col;
        const float bv = bias[o];
#pragma unroll
        for (int reg = 0; reg < 4; ++reg) {
            int ra = tb + quad * 4 + reg;
            int rb = ra + 16;
            out[(size_t)(ra & 7) * N_V * OUT_ + (size_t)(ra >> 3) * OUT_ + o] = acc0[ct][reg] + bv;
            out[(size_t)(rb & 7) * N_V * OUT_ + (size_t)(rb >> 3) * OUT_ + o] = acc1[ct][reg] + bv;
        }
    }
}

// ---------------- launcher ----------------

extern "C" void kernel_launch(void* const* d_in, const int* in_sizes, int n_in,
                              void* d_out, int out_size, void* d_ws, size_t ws_size,
                              hipStream_t stream) {
    const float* x    = (const float*)d_in[0];
    const int*   rows = (const int*)  d_in[1];
    const int*   cols = (const int*)  d_in[2];
    const float* vals = (const float*)d_in[3];
    const float* W    = (const float*)d_in[4];
    const float* bias = (const float*)d_in[5];
    float* out = (float*)d_out;

    const size_t TSZ = (size_t)N_V * BF;           // bf16 elements per T buffer
    ushort_t* T1 = (ushort_t*)d_ws;
    ushort_t* T2 = T1 + TSZ;
    ushort_t* T3 = T2 + TSZ;
    ushort_t* T4 = T3 + TSZ;
    ushort_t* T5 = T4 + TSZ;
    ushort_t* X0 = T5 + TSZ;
    ushort_t* Wfrag = X0 + TSZ;                    // 24576 ushorts
    int*  cnt   = (int*)(Wfrag + 24576);           // NPAIR counters
    int2* edges = (int2*)(cnt + NPAIR + 64);       // NPAIR * PCAP int2

    prep_kernel<<<20136, 256, 0, stream>>>(x, (uint_t*)X0, W, Wfrag, cnt);
    scatter_kernel<<<(NNZ_ + 255) / 256, 256, 0, stream>>>(rows, cols, vals, cnt, edges);

    cheb_pair<false><<<CHEB_WAVES / 4, 256, 0, stream>>>(cnt, edges, X0, nullptr, T1);
    cheb_pair<true ><<<CHEB_WAVES / 4, 256, 0, stream>>>(cnt, edges, T1, X0, T2);
    cheb_pair<true ><<<CHEB_WAVES / 4, 256, 0, stream>>>(cnt, edges, T2, T1, T3);
    cheb_pair<true ><<<CHEB_WAVES / 4, 256, 0, stream>>>(cnt, edges, T3, T2, T4);
    cheb_pair<true ><<<CHEB_WAVES / 4, 256, 0, stream>>>(cnt, edges, T4, T3, T5);

    fc_mfma<<<(N_V * B_) / 128, 256, 0, stream>>>(X0, T1, T2, T3, T4, T5, Wfrag, bias, out);
}